// Round 1
// baseline (214.235 us; speedup 1.0000x reference)
//
#include <hip/hip_runtime.h>

// ---------------------------------------------------------------------------
// Attention_43868795961547: LN -> QKV -> MHA(1025 keys) -> proj
// b=8, n=1024, dim=512, heads=8, dh=64. bf16 MFMA (16x16x32), f32 accum.
// Round 1: correctness-first 6-kernel pipeline.
// ---------------------------------------------------------------------------

typedef __attribute__((ext_vector_type(4))) float f32x4;
typedef __attribute__((ext_vector_type(8))) short bf16x8;

#define MFMA16(a, b, c) __builtin_amdgcn_mfma_f32_16x16x32_bf16(a, b, c, 0, 0, 0)

__device__ __forceinline__ unsigned short f2bf(float f) {
  union { float f; unsigned int u; } c; c.f = f;
  unsigned int u = c.u;
  u += 0x7fffu + ((u >> 16) & 1u);   // RNE
  return (unsigned short)(u >> 16);
}

// ---- kernel 1: convert + transpose weights to bf16 ------------------------
// wqt[n][k] = bf16(w_qkv[k][n])  (1536 x 512)
// wot[n][k] = bf16(w_out[k][n])  (512 x 512)
__global__ __launch_bounds__(256) void k_prep(const float* __restrict__ w_qkv,
                                              const float* __restrict__ w_out,
                                              unsigned short* __restrict__ wqt,
                                              unsigned short* __restrict__ wot) {
  unsigned int gid = blockIdx.x * 256u + threadIdx.x;
  if (gid < 786432u) {
    unsigned int k = gid / 1536u, n = gid % 1536u;
    wqt[(size_t)n * 512u + k] = f2bf(w_qkv[gid]);
  } else if (gid < 786432u + 262144u) {
    unsigned int g = gid - 786432u;
    unsigned int k = g / 512u, n = g % 512u;
    wot[(size_t)n * 512u + k] = f2bf(w_out[g]);
  }
}

// ---- kernel 2: LayerNorm (wave per row) -----------------------------------
// rows 0..8191 -> img -> x_bf (bf16); rows 8192..8199 -> tab -> t_ln (f32)
__global__ __launch_bounds__(256) void k_ln(const float* __restrict__ img,
                                            const float* __restrict__ tab,
                                            const float* __restrict__ ln_w,
                                            const float* __restrict__ ln_b,
                                            unsigned short* __restrict__ x_bf,
                                            float* __restrict__ t_ln) {
  int wid = threadIdx.x >> 6, lane = threadIdx.x & 63;
  int row = blockIdx.x * 4 + wid;
  if (row >= 8200) return;
  const float* src = (row < 8192) ? img + (size_t)row * 512
                                  : tab + (size_t)(row - 8192) * 512;
  float4 v0 = *(const float4*)(src + lane * 8);
  float4 v1 = *(const float4*)(src + lane * 8 + 4);
  float x[8] = {v0.x, v0.y, v0.z, v0.w, v1.x, v1.y, v1.z, v1.w};
  float s = 0.f, sq = 0.f;
  #pragma unroll
  for (int j = 0; j < 8; ++j) { s += x[j]; sq += x[j] * x[j]; }
  #pragma unroll
  for (int off = 32; off >= 1; off >>= 1) {
    s  += __shfl_xor(s, off);
    sq += __shfl_xor(sq, off);
  }
  float mean = s * (1.0f / 512.0f);
  float var  = sq * (1.0f / 512.0f) - mean * mean;
  float rs = rsqrtf(var + 1e-5f);
  float4 w0 = *(const float4*)(ln_w + lane * 8);
  float4 w1 = *(const float4*)(ln_w + lane * 8 + 4);
  float4 b0 = *(const float4*)(ln_b + lane * 8);
  float4 b1 = *(const float4*)(ln_b + lane * 8 + 4);
  float w[8] = {w0.x, w0.y, w0.z, w0.w, w1.x, w1.y, w1.z, w1.w};
  float bb[8] = {b0.x, b0.y, b0.z, b0.w, b1.x, b1.y, b1.z, b1.w};
  float y[8];
  #pragma unroll
  for (int j = 0; j < 8; ++j) y[j] = (x[j] - mean) * rs * w[j] + bb[j];
  if (row < 8192) {
    bf16x8 o;
    #pragma unroll
    for (int j = 0; j < 8; ++j) o[j] = (short)f2bf(y[j]);
    *(bf16x8*)(x_bf + (size_t)row * 512 + lane * 8) = o;
  } else {
    float* dst = t_ln + (size_t)(row - 8192) * 512 + lane * 8;
    *(float4*)dst       = make_float4(y[0], y[1], y[2], y[3]);
    *(float4*)(dst + 4) = make_float4(y[4], y[5], y[6], y[7]);
  }
}

// ---- kernel 3: tab token k/v + zero padding rows --------------------------
// block = (b,h). k_heads row 1024 = tab key; v_t col 1024 = tab value.
// zero k rows 1025..1055 and v cols 1025..1055 (KPAD=1056).
__global__ __launch_bounds__(256) void k_tab(const float* __restrict__ t_ln,
                                             const float* __restrict__ w_tab,
                                             unsigned short* __restrict__ kh,
                                             unsigned short* __restrict__ vt) {
  int bh = blockIdx.x;
  int b = bh >> 3, h = bh & 7;
  int t = threadIdx.x;
  if (t < 128) {
    int part = t >> 6;          // 0 = k, 1 = v
    int d = t & 63;
    int col = 512 + part * 512 + h * 64 + d;
    float s = 0.f;
    for (int k = 0; k < 512; ++k)
      s += t_ln[b * 512 + k] * w_tab[(size_t)k * 1536 + col];
    unsigned short hv = f2bf(s);
    if (part == 0) kh[((size_t)bh * 1056 + 1024) * 64 + d] = hv;
    else           vt[((size_t)bh * 64 + d) * 1056 + 1024] = hv;
  }
  for (int i = t; i < 31 * 64; i += 256) {
    int r = 1025 + (i >> 6), d = i & 63;
    kh[((size_t)bh * 1056 + r) * 64 + d] = 0;
  }
  for (int i = t; i < 64 * 31; i += 256) {
    int d = i / 31, c = 1025 + (i % 31);
    vt[((size_t)bh * 64 + d) * 1056 + c] = 0;
  }
}

// ---- kernel 4: QKV GEMM (bf16 MFMA, 64x64 tile per wave) ------------------
// C[8192][1536] = x_bf[8192][512] @ wqt^T ; scatter into q/k/v head layouts.
__global__ __launch_bounds__(256) void k_qkv(const unsigned short* __restrict__ x_bf,
                                             const unsigned short* __restrict__ wqt,
                                             unsigned short* __restrict__ qh,
                                             unsigned short* __restrict__ kh,
                                             unsigned short* __restrict__ vt) {
  int wave = blockIdx.x * 4 + (threadIdx.x >> 6);
  int lane = threadIdx.x & 63;
  int mt = wave & 127, nt = wave >> 7;      // 128 x 24 tiles of 64x64
  int r0 = mt * 64, c0 = nt * 64;
  int lr = lane & 15, lk = (lane >> 4) * 8;
  f32x4 acc[4][4];
  #pragma unroll
  for (int mi = 0; mi < 4; ++mi)
    #pragma unroll
    for (int ni = 0; ni < 4; ++ni)
      acc[mi][ni] = (f32x4){0.f, 0.f, 0.f, 0.f};
  for (int k0 = 0; k0 < 512; k0 += 32) {
    bf16x8 am[4], bn[4];
    #pragma unroll
    for (int mi = 0; mi < 4; ++mi)
      am[mi] = *(const bf16x8*)(x_bf + (size_t)(r0 + mi * 16 + lr) * 512 + k0 + lk);
    #pragma unroll
    for (int ni = 0; ni < 4; ++ni)
      bn[ni] = *(const bf16x8*)(wqt + (size_t)(c0 + ni * 16 + lr) * 512 + k0 + lk);
    #pragma unroll
    for (int mi = 0; mi < 4; ++mi)
      #pragma unroll
      for (int ni = 0; ni < 4; ++ni)
        acc[mi][ni] = MFMA16(am[mi], bn[ni], acc[mi][ni]);
  }
  #pragma unroll
  for (int ni = 0; ni < 4; ++ni) {
    int col0 = c0 + ni * 16;                 // one 64-block => fixed which/h
    int which = col0 >> 9;
    int hh = (col0 & 511) >> 6;
    int d = (col0 & 63) + lr;
    #pragma unroll
    for (int mi = 0; mi < 4; ++mi)
      #pragma unroll
      for (int reg = 0; reg < 4; ++reg) {
        int row = r0 + mi * 16 + (lane >> 4) * 4 + reg;
        int b = row >> 10, n = row & 1023;
        int bh = b * 8 + hh;
        unsigned short hv = f2bf(acc[mi][ni][reg]);
        if (which == 0)      qh[((size_t)bh * 1024 + n) * 64 + d] = hv;
        else if (which == 1) kh[((size_t)bh * 1056 + n) * 64 + d] = hv;
        else                 vt[((size_t)bh * 64 + d) * 1056 + n] = hv;
      }
  }
}

// ---- kernel 5: flash attention (wave = (b,h, 16-row q-tile)) --------------
// 33 key-tiles of 32 (keys padded 1025 -> 1056, masked past 1024).
__global__ __launch_bounds__(256) void k_attn(const unsigned short* __restrict__ qh,
                                              const unsigned short* __restrict__ kh,
                                              const unsigned short* __restrict__ vt,
                                              unsigned short* __restrict__ ao) {
  __shared__ __align__(16) unsigned short p_lds[4][16][32];
  int wid = threadIdx.x >> 6, lane = threadIdx.x & 63;
  int wave = blockIdx.x * 4 + wid;
  int bh = wave >> 6, qt = wave & 63;
  int q0 = qt * 16;
  const unsigned short* Q = qh + (size_t)bh * 1024 * 64;
  const unsigned short* K = kh + (size_t)bh * 1056 * 64;
  const unsigned short* V = vt + (size_t)bh * 64 * 1056;
  int lr = lane & 15, lg = lane >> 4;
  bf16x8 aq[2];
  #pragma unroll
  for (int kc = 0; kc < 2; ++kc)
    aq[kc] = *(const bf16x8*)(Q + (size_t)(q0 + lr) * 64 + kc * 32 + lg * 8);
  f32x4 of[4];
  float m[4], lsum[4];
  #pragma unroll
  for (int cf = 0; cf < 4; ++cf) of[cf] = (f32x4){0.f, 0.f, 0.f, 0.f};
  #pragma unroll
  for (int r = 0; r < 4; ++r) { m[r] = -1e30f; lsum[r] = 0.f; }

  for (int kt = 0; kt < 33; ++kt) {
    // S = Q K^T for 32 keys (two 16-col fragments)
    f32x4 sfr[2];
    sfr[0] = (f32x4){0.f, 0.f, 0.f, 0.f};
    sfr[1] = (f32x4){0.f, 0.f, 0.f, 0.f};
    #pragma unroll
    for (int cj = 0; cj < 2; ++cj)
      #pragma unroll
      for (int kc = 0; kc < 2; ++kc) {
        bf16x8 bk = *(const bf16x8*)(K + (size_t)(kt * 32 + cj * 16 + lr) * 64 + kc * 32 + lg * 8);
        sfr[cj] = MFMA16(aq[kc], bk, sfr[cj]);
      }
    // scale + mask (keys > 1024 invalid)
    float sv[2][4];
    int key = kt * 32 + lr;
    #pragma unroll
    for (int cj = 0; cj < 2; ++cj) {
      bool valid = (key + cj * 16) <= 1024;
      #pragma unroll
      for (int reg = 0; reg < 4; ++reg)
        sv[cj][reg] = valid ? sfr[cj][reg] * 0.125f : -1e30f;
    }
    // row max over 32 cols (16-lane groups hold rows 4*lg..4*lg+3)
    float tmax[4];
    #pragma unroll
    for (int reg = 0; reg < 4; ++reg) tmax[reg] = fmaxf(sv[0][reg], sv[1][reg]);
    #pragma unroll
    for (int off = 8; off >= 1; off >>= 1)
      #pragma unroll
      for (int reg = 0; reg < 4; ++reg)
        tmax[reg] = fmaxf(tmax[reg], __shfl_xor(tmax[reg], off));
    // online softmax update
    float p[2][4], rsum[4];
    #pragma unroll
    for (int reg = 0; reg < 4; ++reg) {
      float mn = fmaxf(m[reg], tmax[reg]);
      float alpha = __expf(m[reg] - mn);
      m[reg] = mn;
      p[0][reg] = __expf(sv[0][reg] - mn);
      p[1][reg] = __expf(sv[1][reg] - mn);
      rsum[reg] = p[0][reg] + p[1][reg];
      lsum[reg] *= alpha;
      #pragma unroll
      for (int cf = 0; cf < 4; ++cf) of[cf][reg] *= alpha;
    }
    #pragma unroll
    for (int off = 8; off >= 1; off >>= 1)
      #pragma unroll
      for (int reg = 0; reg < 4; ++reg)
        rsum[reg] += __shfl_xor(rsum[reg], off);
    #pragma unroll
    for (int reg = 0; reg < 4; ++reg) lsum[reg] += rsum[reg];
    // P -> bf16 A-fragment via per-wave LDS slab
    #pragma unroll
    for (int cj = 0; cj < 2; ++cj)
      #pragma unroll
      for (int reg = 0; reg < 4; ++reg)
        p_lds[wid][lg * 4 + reg][cj * 16 + lr] = f2bf(p[cj][reg]);
    __syncthreads();
    bf16x8 ap = *(const bf16x8*)(&p_lds[wid][lr][lg * 8]);
    // O += P @ V  (V transposed: [d][key])
    #pragma unroll
    for (int cf = 0; cf < 4; ++cf) {
      bf16x8 bv = *(const bf16x8*)(V + (size_t)(cf * 16 + lr) * 1056 + kt * 32 + lg * 8);
      of[cf] = MFMA16(ap, bv, of[cf]);
    }
  }
  // epilogue: divide by lsum, store bf16 to attn_out [8192][512]
  int b = bh >> 3, h = bh & 7;
  #pragma unroll
  for (int cf = 0; cf < 4; ++cf)
    #pragma unroll
    for (int reg = 0; reg < 4; ++reg) {
      int row = q0 + lg * 4 + reg;
      int col = h * 64 + cf * 16 + lr;
      float v = of[cf][reg] / lsum[reg];
      ao[((size_t)b * 1024 + row) * 512 + col] = f2bf(v);
    }
}

// ---- kernel 6: output GEMM + bias (f32 out) -------------------------------
__global__ __launch_bounds__(256) void k_out(const unsigned short* __restrict__ ao,
                                             const unsigned short* __restrict__ wot,
                                             const float* __restrict__ b_out,
                                             float* __restrict__ out) {
  int wave = blockIdx.x * 4 + (threadIdx.x >> 6);
  int lane = threadIdx.x & 63;
  int mt = wave & 127, nt = wave >> 7;      // 128 x 8 tiles
  int r0 = mt * 64, c0 = nt * 64;
  int lr = lane & 15, lk = (lane >> 4) * 8;
  f32x4 acc[4][4];
  #pragma unroll
  for (int mi = 0; mi < 4; ++mi)
    #pragma unroll
    for (int ni = 0; ni < 4; ++ni)
      acc[mi][ni] = (f32x4){0.f, 0.f, 0.f, 0.f};
  for (int k0 = 0; k0 < 512; k0 += 32) {
    bf16x8 am[4], bn[4];
    #pragma unroll
    for (int mi = 0; mi < 4; ++mi)
      am[mi] = *(const bf16x8*)(ao + (size_t)(r0 + mi * 16 + lr) * 512 + k0 + lk);
    #pragma unroll
    for (int ni = 0; ni < 4; ++ni)
      bn[ni] = *(const bf16x8*)(wot + (size_t)(c0 + ni * 16 + lr) * 512 + k0 + lk);
    #pragma unroll
    for (int mi = 0; mi < 4; ++mi)
      #pragma unroll
      for (int ni = 0; ni < 4; ++ni)
        acc[mi][ni] = MFMA16(am[mi], bn[ni], acc[mi][ni]);
  }
  #pragma unroll
  for (int ni = 0; ni < 4; ++ni) {
    int col = c0 + ni * 16 + lr;
    float bias = b_out[col];
    #pragma unroll
    for (int mi = 0; mi < 4; ++mi)
      #pragma unroll
      for (int reg = 0; reg < 4; ++reg) {
        int row = r0 + mi * 16 + (lane >> 4) * 4 + reg;
        out[(size_t)row * 512 + col] = acc[mi][ni][reg] + bias;
      }
  }
}

// ---------------------------------------------------------------------------
extern "C" void kernel_launch(void* const* d_in, const int* in_sizes, int n_in,
                              void* d_out, int out_size, void* d_ws, size_t ws_size,
                              hipStream_t stream) {
  const float* img       = (const float*)d_in[0];
  const float* tab       = (const float*)d_in[1];
  const float* w_qkv     = (const float*)d_in[2];
  const float* w_tab_qkv = (const float*)d_in[3];
  const float* w_out     = (const float*)d_in[4];
  const float* b_out     = (const float*)d_in[5];
  const float* ln_w      = (const float*)d_in[6];
  const float* ln_b      = (const float*)d_in[7];
  char* ws = (char*)d_ws;
  // ws layout (all 16B-aligned)
  unsigned short* x_bf = (unsigned short*)(ws);             //  8 MiB
  unsigned short* wqt  = (unsigned short*)(ws + 8388608);   //  1.5 MiB
  unsigned short* wot  = (unsigned short*)(ws + 9961472);   //  0.5 MiB
  unsigned short* qh   = (unsigned short*)(ws + 10485760);  //  8 MiB
  unsigned short* kh   = (unsigned short*)(ws + 18874368);  //  8.25 MiB
  unsigned short* vt   = (unsigned short*)(ws + 27525120);  //  8.25 MiB
  unsigned short* ao   = (unsigned short*)(ws + 36175872);  //  8 MiB
  float*          t_ln = (float*)(ws + 44564480);           //  16 KiB
  float* out = (float*)d_out;

  hipLaunchKernelGGL(k_prep, dim3(4096), dim3(256), 0, stream, w_qkv, w_out, wqt, wot);
  hipLaunchKernelGGL(k_ln,   dim3(2050), dim3(256), 0, stream, img, tab, ln_w, ln_b, x_bf, t_ln);
  hipLaunchKernelGGL(k_tab,  dim3(64),   dim3(256), 0, stream, t_ln, w_tab_qkv, kh, vt);
  hipLaunchKernelGGL(k_qkv,  dim3(768),  dim3(256), 0, stream, x_bf, wqt, qh, kh, vt);
  hipLaunchKernelGGL(k_attn, dim3(1024), dim3(256), 0, stream, qh, kh, vt, ao);
  hipLaunchKernelGGL(k_out,  dim3(256),  dim3(256), 0, stream, ao, wot, b_out, out);
}

// Round 2
// 178.708 us; speedup vs baseline: 1.1988x; 1.1988x over previous
//
#include <hip/hip_runtime.h>

// ---------------------------------------------------------------------------
// Attention_43868795961547: LN -> QKV -> MHA(1025 keys) -> proj
// b=8, n=1024, dim=512, heads=8, dh=64. bf16 MFMA, f32 accum.
// Round 2: k_attn rewritten with swapped QK^T (32x32x16), in-register softmax
// via cvt_pk_bf16 + permlane32_swap, defer-max, no LDS/barriers in loop.
// ---------------------------------------------------------------------------

typedef __attribute__((ext_vector_type(4))) float f32x4;
typedef __attribute__((ext_vector_type(16))) float f32x16;
typedef __attribute__((ext_vector_type(8))) short bf16x8;

#define MFMA16(a, b, c) __builtin_amdgcn_mfma_f32_16x16x32_bf16(a, b, c, 0, 0, 0)
#define MFMA32(a, b, c) __builtin_amdgcn_mfma_f32_32x32x16_bf16(a, b, c, 0, 0, 0)

// Q pre-scale: dots*0.125 in exp2-domain => fold 0.125*log2(e) into Q.
#define QSCALE 0.18033688011112042f

__device__ __forceinline__ unsigned short f2bf(float f) {
  union { float f; unsigned int u; } c; c.f = f;
  unsigned int u = c.u;
  u += 0x7fffu + ((u >> 16) & 1u);   // RNE
  return (unsigned short)(u >> 16);
}

__device__ __forceinline__ unsigned int cvtpk_bf16(float lo, float hi) {
  unsigned int r;
  asm("v_cvt_pk_bf16_f32 %0, %1, %2" : "=v"(r) : "v"(lo), "v"(hi));
  return r;
}

// ---- kernel 1: convert + transpose weights to bf16 ------------------------
__global__ __launch_bounds__(256) void k_prep(const float* __restrict__ w_qkv,
                                              const float* __restrict__ w_out,
                                              unsigned short* __restrict__ wqt,
                                              unsigned short* __restrict__ wot) {
  unsigned int gid = blockIdx.x * 256u + threadIdx.x;
  if (gid < 786432u) {
    unsigned int k = gid / 1536u, n = gid % 1536u;
    wqt[(size_t)n * 512u + k] = f2bf(w_qkv[gid]);
  } else if (gid < 786432u + 262144u) {
    unsigned int g = gid - 786432u;
    unsigned int k = g / 512u, n = g % 512u;
    wot[(size_t)n * 512u + k] = f2bf(w_out[g]);
  }
}

// ---- kernel 2: LayerNorm (wave per row) -----------------------------------
__global__ __launch_bounds__(256) void k_ln(const float* __restrict__ img,
                                            const float* __restrict__ tab,
                                            const float* __restrict__ ln_w,
                                            const float* __restrict__ ln_b,
                                            unsigned short* __restrict__ x_bf,
                                            float* __restrict__ t_ln) {
  int wid = threadIdx.x >> 6, lane = threadIdx.x & 63;
  int row = blockIdx.x * 4 + wid;
  if (row >= 8200) return;
  const float* src = (row < 8192) ? img + (size_t)row * 512
                                  : tab + (size_t)(row - 8192) * 512;
  float4 v0 = *(const float4*)(src + lane * 8);
  float4 v1 = *(const float4*)(src + lane * 8 + 4);
  float x[8] = {v0.x, v0.y, v0.z, v0.w, v1.x, v1.y, v1.z, v1.w};
  float s = 0.f, sq = 0.f;
  #pragma unroll
  for (int j = 0; j < 8; ++j) { s += x[j]; sq += x[j] * x[j]; }
  #pragma unroll
  for (int off = 32; off >= 1; off >>= 1) {
    s  += __shfl_xor(s, off);
    sq += __shfl_xor(sq, off);
  }
  float mean = s * (1.0f / 512.0f);
  float var  = sq * (1.0f / 512.0f) - mean * mean;
  float rs = rsqrtf(var + 1e-5f);
  float4 w0 = *(const float4*)(ln_w + lane * 8);
  float4 w1 = *(const float4*)(ln_w + lane * 8 + 4);
  float4 b0 = *(const float4*)(ln_b + lane * 8);
  float4 b1 = *(const float4*)(ln_b + lane * 8 + 4);
  float w[8] = {w0.x, w0.y, w0.z, w0.w, w1.x, w1.y, w1.z, w1.w};
  float bb[8] = {b0.x, b0.y, b0.z, b0.w, b1.x, b1.y, b1.z, b1.w};
  float y[8];
  #pragma unroll
  for (int j = 0; j < 8; ++j) y[j] = (x[j] - mean) * rs * w[j] + bb[j];
  if (row < 8192) {
    bf16x8 o;
    #pragma unroll
    for (int j = 0; j < 8; ++j) o[j] = (short)f2bf(y[j]);
    *(bf16x8*)(x_bf + (size_t)row * 512 + lane * 8) = o;
  } else {
    float* dst = t_ln + (size_t)(row - 8192) * 512 + lane * 8;
    *(float4*)dst       = make_float4(y[0], y[1], y[2], y[3]);
    *(float4*)(dst + 4) = make_float4(y[4], y[5], y[6], y[7]);
  }
}

// ---- kernel 3: tab token k/v (block per batch, coalesced) -----------------
__global__ __launch_bounds__(256) void k_tab(const float* __restrict__ t_ln,
                                             const float* __restrict__ w_tab,
                                             unsigned short* __restrict__ kh,
                                             unsigned short* __restrict__ vt) {
  __shared__ float tl[512];
  int b = blockIdx.x, t = threadIdx.x;
  tl[t] = t_ln[b * 512 + t];
  tl[t + 256] = t_ln[b * 512 + t + 256];
  __syncthreads();
  float s[4] = {0.f, 0.f, 0.f, 0.f};
  for (int k = 0; k < 512; ++k) {
    float a = tl[k];
    #pragma unroll
    for (int i = 0; i < 4; ++i)
      s[i] += a * w_tab[(size_t)k * 1536 + 512 + i * 256 + t];
  }
  #pragma unroll
  for (int i = 0; i < 4; ++i) {
    int g = i * 256 + t;          // 0..1023 over [k | v] x [h] x [d]
    int part = g >> 9, hd = g & 511, h = hd >> 6, d = hd & 63;
    int bh = b * 8 + h;
    unsigned short hv = f2bf(s[i]);
    if (part == 0) kh[((size_t)bh * 1056 + 1024) * 64 + d] = hv;
    else           vt[((size_t)bh * 64 + d) * 1056 + 1024] = hv;
  }
}

// ---- kernel 4: QKV GEMM (bf16 MFMA, 64x64 tile per wave) ------------------
// Q output is pre-scaled by QSCALE (softmax scale folded, exp2 domain).
__global__ __launch_bounds__(256) void k_qkv(const unsigned short* __restrict__ x_bf,
                                             const unsigned short* __restrict__ wqt,
                                             unsigned short* __restrict__ qh,
                                             unsigned short* __restrict__ kh,
                                             unsigned short* __restrict__ vt) {
  int wave = blockIdx.x * 4 + (threadIdx.x >> 6);
  int lane = threadIdx.x & 63;
  int mt = wave & 127, nt = wave >> 7;      // 128 x 24 tiles of 64x64
  int r0 = mt * 64, c0 = nt * 64;
  int lr = lane & 15, lk = (lane >> 4) * 8;
  f32x4 acc[4][4];
  #pragma unroll
  for (int mi = 0; mi < 4; ++mi)
    #pragma unroll
    for (int ni = 0; ni < 4; ++ni)
      acc[mi][ni] = (f32x4){0.f, 0.f, 0.f, 0.f};
  for (int k0 = 0; k0 < 512; k0 += 32) {
    bf16x8 am[4], bn[4];
    #pragma unroll
    for (int mi = 0; mi < 4; ++mi)
      am[mi] = *(const bf16x8*)(x_bf + (size_t)(r0 + mi * 16 + lr) * 512 + k0 + lk);
    #pragma unroll
    for (int ni = 0; ni < 4; ++ni)
      bn[ni] = *(const bf16x8*)(wqt + (size_t)(c0 + ni * 16 + lr) * 512 + k0 + lk);
    #pragma unroll
    for (int mi = 0; mi < 4; ++mi)
      #pragma unroll
      for (int ni = 0; ni < 4; ++ni)
        acc[mi][ni] = MFMA16(am[mi], bn[ni], acc[mi][ni]);
  }
  #pragma unroll
  for (int ni = 0; ni < 4; ++ni) {
    int col0 = c0 + ni * 16;                 // one 64-block => fixed which/h
    int which = col0 >> 9;
    int hh = (col0 & 511) >> 6;
    int d = (col0 & 63) + lr;
    #pragma unroll
    for (int mi = 0; mi < 4; ++mi)
      #pragma unroll
      for (int reg = 0; reg < 4; ++reg) {
        int row = r0 + mi * 16 + (lane >> 4) * 4 + reg;
        int b = row >> 10, n = row & 1023;
        int bh = b * 8 + hh;
        float v = acc[mi][ni][reg];
        if (which == 0) {
          qh[((size_t)bh * 1024 + n) * 64 + d] = f2bf(v * QSCALE);
        } else if (which == 1) {
          kh[((size_t)bh * 1056 + n) * 64 + d] = f2bf(v);
        } else {
          vt[((size_t)bh * 64 + d) * 1056 + n] = f2bf(v);
        }
      }
  }
}

// ---- kernel 5: flash attention, swapped-operand 32x32 MFMA ----------------
// wave = (bh, 32-row q-tile). S^T = mfma(K, Q): col=q=lane&31, keys in regs.
// Softmax in-register; P->bf16 via cvt_pk + permlane32_swap; PV swapped
// (A=V^T, B=P) so O^T cols stay q=lane&31. 33 key-tiles of 32; tile 32 has
// only key 1024 valid (tab token), rest masked.
__global__ __launch_bounds__(256) void k_attn(const unsigned short* __restrict__ qh,
                                              const unsigned short* __restrict__ kh,
                                              const unsigned short* __restrict__ vt,
                                              unsigned short* __restrict__ ao) {
  int wid = threadIdx.x >> 6, lane = threadIdx.x & 63;
  int wave = blockIdx.x * 4 + wid;
  int bh = wave >> 5, qt = wave & 31;
  int q0 = qt * 32;
  int lq = lane & 31;          // q / key / d row within 32-group
  int half = lane >> 5;        // k-subchunk selector
  const unsigned short* Q = qh + (size_t)bh * 1024 * 64;
  const unsigned short* K = kh + (size_t)bh * 1056 * 64;
  const unsigned short* V = vt + (size_t)bh * 64 * 1056;

  const unsigned short* qlane = Q + (size_t)(q0 + lq) * 64 + half * 8;
  const unsigned short* klane = K + (size_t)lq * 64 + half * 8;
  const unsigned short* vlane = V + (size_t)lq * 1056 + half * 8;

  // Q fragments (B-operand), d-chunks of 16
  bf16x8 qf[4];
  #pragma unroll
  for (int dt = 0; dt < 4; ++dt)
    qf[dt] = *(const bf16x8*)(qlane + dt * 16);

  // K fragments for tile 0
  bf16x8 kf[4], kfn[4];
  #pragma unroll
  for (int dt = 0; dt < 4; ++dt)
    kf[dt] = *(const bf16x8*)(klane + dt * 16);

  f32x16 o0 = (f32x16)(0.0f), o1 = (f32x16)(0.0f);
  float m = -1e30f, lsum = 0.f;

  for (int kt = 0; kt < 33; ++kt) {
    // V fragments for this tile (A-operand of swapped PV)
    bf16x8 vf00 = *(const bf16x8*)(vlane + kt * 32);
    bf16x8 vf01 = *(const bf16x8*)(vlane + kt * 32 + 16);
    bf16x8 vf10 = *(const bf16x8*)(vlane + 32 * 1056 + kt * 32);
    bf16x8 vf11 = *(const bf16x8*)(vlane + 32 * 1056 + kt * 32 + 16);
    // prefetch next K tile
    if (kt < 32) {
      #pragma unroll
      for (int dt = 0; dt < 4; ++dt)
        kfn[dt] = *(const bf16x8*)(klane + (kt + 1) * 2048 + dt * 16);
    }
    // S^T[key][q] (exp2 domain; scale folded into Q)
    f32x16 s = (f32x16)(0.0f);
    #pragma unroll
    for (int dt = 0; dt < 4; ++dt)
      s = MFMA32(kf[dt], qf[dt], s);
    // mask the tab tile: only key 1024 (reg 0, half 0) valid
    if (kt == 32) {
      #pragma unroll
      for (int reg = 0; reg < 16; ++reg) {
        if (reg == 0) { if (half) s[0] = -1e30f; }
        else s[reg] = -1e30f;
      }
    }
    // row max over this tile (15 reg-max + cross-half)
    float pmax = s[0];
    #pragma unroll
    for (int reg = 1; reg < 16; ++reg) pmax = fmaxf(pmax, s[reg]);
    pmax = fmaxf(pmax, __shfl_xor(pmax, 32));
    // defer-max online rescale (THR=8 in exp2 domain)
    if (!__all(pmax <= m + 8.0f)) {
      float mnew = fmaxf(m, pmax);
      float al = __builtin_amdgcn_exp2f(m - mnew);
      lsum *= al;
      #pragma unroll
      for (int reg = 0; reg < 16; ++reg) { o0[reg] *= al; o1[reg] *= al; }
      m = mnew;
    }
    // p = exp2(s - m), local sum
    float p[16];
    float ls = 0.f;
    #pragma unroll
    for (int reg = 0; reg < 16; ++reg) {
      p[reg] = __builtin_amdgcn_exp2f(s[reg] - m);
      ls += p[reg];
    }
    lsum += ls;
    // pack P -> bf16 B-fragments (chunk0 = keys 0..15, chunk1 = 16..31)
    unsigned int c0x0 = cvtpk_bf16(p[0],  p[1]);
    unsigned int c0x1 = cvtpk_bf16(p[2],  p[3]);
    unsigned int c0y0 = cvtpk_bf16(p[4],  p[5]);
    unsigned int c0y1 = cvtpk_bf16(p[6],  p[7]);
    unsigned int c1x0 = cvtpk_bf16(p[8],  p[9]);
    unsigned int c1x1 = cvtpk_bf16(p[10], p[11]);
    unsigned int c1y0 = cvtpk_bf16(p[12], p[13]);
    unsigned int c1y1 = cvtpk_bf16(p[14], p[15]);
    asm volatile("v_permlane32_swap_b32 %0, %1" : "+v"(c0x0), "+v"(c0y0));
    asm volatile("v_permlane32_swap_b32 %0, %1" : "+v"(c0x1), "+v"(c0y1));
    asm volatile("v_permlane32_swap_b32 %0, %1" : "+v"(c1x0), "+v"(c1y0));
    asm volatile("v_permlane32_swap_b32 %0, %1" : "+v"(c1x1), "+v"(c1y1));
    union { unsigned int w[4]; bf16x8 v; } f0, f1;
    f0.w[0] = c0x0; f0.w[1] = c0x1; f0.w[2] = c0y0; f0.w[3] = c0y1;
    f1.w[0] = c1x0; f1.w[1] = c1x1; f1.w[2] = c1y0; f1.w[3] = c1y1;
    // O^T += V^T P  (2 d-tiles x 2 key-chunks)
    o0 = MFMA32(vf00, f0.v, o0);
    o0 = MFMA32(vf01, f1.v, o0);
    o1 = MFMA32(vf10, f0.v, o1);
    o1 = MFMA32(vf11, f1.v, o1);
    // rotate K buffers
    #pragma unroll
    for (int dt = 0; dt < 4; ++dt) kf[dt] = kfn[dt];
  }
  // combine half-sums, normalize, store
  lsum += __shfl_xor(lsum, 32);
  float rl = 1.0f / lsum;
  int b = bh >> 3, h = bh & 7;
  unsigned short* aorow = ao + ((size_t)(b * 1024 + q0 + lq)) * 512 + h * 64;
  #pragma unroll
  for (int dt2 = 0; dt2 < 2; ++dt2) {
    #pragma unroll
    for (int g = 0; g < 4; ++g) {
      ushort4 pk;
      float v0 = (dt2 ? o1[4 * g + 0] : o0[4 * g + 0]) * rl;
      float v1 = (dt2 ? o1[4 * g + 1] : o0[4 * g + 1]) * rl;
      float v2 = (dt2 ? o1[4 * g + 2] : o0[4 * g + 2]) * rl;
      float v3 = (dt2 ? o1[4 * g + 3] : o0[4 * g + 3]) * rl;
      pk.x = f2bf(v0); pk.y = f2bf(v1); pk.z = f2bf(v2); pk.w = f2bf(v3);
      *(ushort4*)(aorow + dt2 * 32 + 8 * g + 4 * half) = pk;
    }
  }
}

// ---- kernel 6: output GEMM + bias (f32 out) -------------------------------
__global__ __launch_bounds__(256) void k_out(const unsigned short* __restrict__ ao,
                                             const unsigned short* __restrict__ wot,
                                             const float* __restrict__ b_out,
                                             float* __restrict__ out) {
  int wave = blockIdx.x * 4 + (threadIdx.x >> 6);
  int lane = threadIdx.x & 63;
  int mt = wave & 127, nt = wave >> 7;      // 128 x 8 tiles
  int r0 = mt * 64, c0 = nt * 64;
  int lr = lane & 15, lk = (lane >> 4) * 8;
  f32x4 acc[4][4];
  #pragma unroll
  for (int mi = 0; mi < 4; ++mi)
    #pragma unroll
    for (int ni = 0; ni < 4; ++ni)
      acc[mi][ni] = (f32x4){0.f, 0.f, 0.f, 0.f};
  for (int k0 = 0; k0 < 512; k0 += 32) {
    bf16x8 am[4], bn[4];
    #pragma unroll
    for (int mi = 0; mi < 4; ++mi)
      am[mi] = *(const bf16x8*)(ao + (size_t)(r0 + mi * 16 + lr) * 512 + k0 + lk);
    #pragma unroll
    for (int ni = 0; ni < 4; ++ni)
      bn[ni] = *(const bf16x8*)(wot + (size_t)(c0 + ni * 16 + lr) * 512 + k0 + lk);
    #pragma unroll
    for (int mi = 0; mi < 4; ++mi)
      #pragma unroll
      for (int ni = 0; ni < 4; ++ni)
        acc[mi][ni] = MFMA16(am[mi], bn[ni], acc[mi][ni]);
  }
  #pragma unroll
  for (int ni = 0; ni < 4; ++ni) {
    int col = c0 + ni * 16 + lr;
    float bias = b_out[col];
    #pragma unroll
    for (int mi = 0; mi < 4; ++mi)
      #pragma unroll
      for (int reg = 0; reg < 4; ++reg) {
        int row = r0 + mi * 16 + (lane >> 4) * 4 + reg;
        out[(size_t)row * 512 + col] = acc[mi][ni][reg] + bias;
      }
  }
}

// ---------------------------------------------------------------------------
extern "C" void kernel_launch(void* const* d_in, const int* in_sizes, int n_in,
                              void* d_out, int out_size, void* d_ws, size_t ws_size,
                              hipStream_t stream) {
  const float* img       = (const float*)d_in[0];
  const float* tab       = (const float*)d_in[1];
  const float* w_qkv     = (const float*)d_in[2];
  const float* w_tab_qkv = (const float*)d_in[3];
  const float* w_out     = (const float*)d_in[4];
  const float* b_out     = (const float*)d_in[5];
  const float* ln_w      = (const float*)d_in[6];
  const float* ln_b      = (const float*)d_in[7];
  char* ws = (char*)d_ws;
  unsigned short* x_bf = (unsigned short*)(ws);             //  8 MiB
  unsigned short* wqt  = (unsigned short*)(ws + 8388608);   //  1.5 MiB
  unsigned short* wot  = (unsigned short*)(ws + 9961472);   //  0.5 MiB
  unsigned short* qh   = (unsigned short*)(ws + 10485760);  //  8 MiB
  unsigned short* kh   = (unsigned short*)(ws + 18874368);  //  8.25 MiB
  unsigned short* vt   = (unsigned short*)(ws + 27525120);  //  8.25 MiB
  unsigned short* ao   = (unsigned short*)(ws + 36175872);  //  8 MiB
  float*          t_ln = (float*)(ws + 44564480);           //  16 KiB
  float* out = (float*)d_out;

  hipLaunchKernelGGL(k_prep, dim3(4096), dim3(256), 0, stream, w_qkv, w_out, wqt, wot);
  hipLaunchKernelGGL(k_ln,   dim3(2050), dim3(256), 0, stream, img, tab, ln_w, ln_b, x_bf, t_ln);
  hipLaunchKernelGGL(k_tab,  dim3(8),    dim3(256), 0, stream, t_ln, w_tab_qkv, kh, vt);
  hipLaunchKernelGGL(k_qkv,  dim3(768),  dim3(256), 0, stream, x_bf, wqt, qh, kh, vt);
  hipLaunchKernelGGL(k_attn, dim3(512),  dim3(256), 0, stream, qh, kh, vt, ao);
  hipLaunchKernelGGL(k_out,  dim3(256),  dim3(256), 0, stream, ao, wot, b_out, out);
}

// Round 3
// 147.154 us; speedup vs baseline: 1.4559x; 1.2144x over previous
//
#include <hip/hip_runtime.h>

// ---------------------------------------------------------------------------
// Attention_43868795961547: LN -> QKV -> MHA(1025 keys) -> proj
// b=8, n=1024, dim=512, heads=8, dh=64. bf16 MFMA, f32 accum.
// Round 3: m97-structure GEMMs (128x128 tile, global_load_lds w=16, BK=32),
// tiled-transpose k_prep. k_attn unchanged from round 2.
// ---------------------------------------------------------------------------

typedef __attribute__((ext_vector_type(4))) float f32x4;
typedef __attribute__((ext_vector_type(16))) float f32x16;
typedef __attribute__((ext_vector_type(8))) short bf16x8;

#define MFMA16(a, b, c) __builtin_amdgcn_mfma_f32_16x16x32_bf16(a, b, c, 0, 0, 0)
#define MFMA32(a, b, c) __builtin_amdgcn_mfma_f32_32x32x16_bf16(a, b, c, 0, 0, 0)

#define GLD16(gsrc, ldst)                                                     \
  __builtin_amdgcn_global_load_lds(                                           \
      (const __attribute__((address_space(1))) void*)(gsrc),                  \
      (__attribute__((address_space(3))) void*)(ldst), 16, 0, 0)

// Q pre-scale: dots*0.125 in exp2-domain => fold 0.125*log2(e) into Q.
#define QSCALE 0.18033688011112042f

__device__ __forceinline__ unsigned short f2bf(float f) {
  union { float f; unsigned int u; } c; c.f = f;
  unsigned int u = c.u;
  u += 0x7fffu + ((u >> 16) & 1u);   // RNE
  return (unsigned short)(u >> 16);
}

__device__ __forceinline__ unsigned int cvtpk_bf16(float lo, float hi) {
  unsigned int r;
  asm("v_cvt_pk_bf16_f32 %0, %1, %2" : "=v"(r) : "v"(lo), "v"(hi));
  return r;
}

// ---- kernel 1: tiled transpose+convert weights to bf16 --------------------
// blocks 0..191: w_qkv (512x1536) -> wqt (1536x512)
// blocks 192..255: w_out (512x512) -> wot (512x512)
__global__ __launch_bounds__(256) void k_prep(const float* __restrict__ w_qkv,
                                              const float* __restrict__ w_out,
                                              unsigned short* __restrict__ wqt,
                                              unsigned short* __restrict__ wot) {
  __shared__ unsigned short t[64][68];
  int blk = blockIdx.x, tid = threadIdx.x;
  const float* src;
  unsigned short* dst;
  int k0, n0, ldin;
  if (blk < 192) {
    int ti = blk >> 5, tj = blk & 31;            // 6 x 32? no: 8 k-tiles x 24 n-tiles
    ti = blk / 24; tj = blk % 24;
    k0 = ti * 64; n0 = tj * 64; ldin = 1536;
    src = w_qkv; dst = wqt;
  } else {
    int g = blk - 192;
    int ti = g >> 3, tj = g & 7;
    k0 = ti * 64; n0 = tj * 64; ldin = 512;
    src = w_out; dst = wot;
  }
  int rr = tid >> 4, c4 = (tid & 15) * 4;
  #pragma unroll
  for (int i = 0; i < 4; ++i) {
    int r = i * 16 + rr;                         // k-row within tile
    float4 v = *(const float4*)(src + (size_t)(k0 + r) * ldin + n0 + c4);
    t[c4 + 0][r] = f2bf(v.x);
    t[c4 + 1][r] = f2bf(v.y);
    t[c4 + 2][r] = f2bf(v.z);
    t[c4 + 3][r] = f2bf(v.w);
  }
  __syncthreads();
  #pragma unroll
  for (int i = 0; i < 4; ++i) {
    int r = i * 16 + rr;                         // n-row of output tile
    ushort4 w = *(const ushort4*)&t[r][c4];
    *(ushort4*)(dst + (size_t)(n0 + r) * 512 + k0 + c4) = w;
  }
}

// ---- kernel 2: LayerNorm (wave per row) -----------------------------------
__global__ __launch_bounds__(256) void k_ln(const float* __restrict__ img,
                                            const float* __restrict__ tab,
                                            const float* __restrict__ ln_w,
                                            const float* __restrict__ ln_b,
                                            unsigned short* __restrict__ x_bf,
                                            float* __restrict__ t_ln) {
  int wid = threadIdx.x >> 6, lane = threadIdx.x & 63;
  int row = blockIdx.x * 4 + wid;
  if (row >= 8200) return;
  const float* src = (row < 8192) ? img + (size_t)row * 512
                                  : tab + (size_t)(row - 8192) * 512;
  float4 v0 = *(const float4*)(src + lane * 8);
  float4 v1 = *(const float4*)(src + lane * 8 + 4);
  float x[8] = {v0.x, v0.y, v0.z, v0.w, v1.x, v1.y, v1.z, v1.w};
  float s = 0.f, sq = 0.f;
  #pragma unroll
  for (int j = 0; j < 8; ++j) { s += x[j]; sq += x[j] * x[j]; }
  #pragma unroll
  for (int off = 32; off >= 1; off >>= 1) {
    s  += __shfl_xor(s, off);
    sq += __shfl_xor(sq, off);
  }
  float mean = s * (1.0f / 512.0f);
  float var  = sq * (1.0f / 512.0f) - mean * mean;
  float rs = rsqrtf(var + 1e-5f);
  float4 w0 = *(const float4*)(ln_w + lane * 8);
  float4 w1 = *(const float4*)(ln_w + lane * 8 + 4);
  float4 b0 = *(const float4*)(ln_b + lane * 8);
  float4 b1 = *(const float4*)(ln_b + lane * 8 + 4);
  float w[8] = {w0.x, w0.y, w0.z, w0.w, w1.x, w1.y, w1.z, w1.w};
  float bb[8] = {b0.x, b0.y, b0.z, b0.w, b1.x, b1.y, b1.z, b1.w};
  float y[8];
  #pragma unroll
  for (int j = 0; j < 8; ++j) y[j] = (x[j] - mean) * rs * w[j] + bb[j];
  if (row < 8192) {
    bf16x8 o;
    #pragma unroll
    for (int j = 0; j < 8; ++j) o[j] = (short)f2bf(y[j]);
    *(bf16x8*)(x_bf + (size_t)row * 512 + lane * 8) = o;
  } else {
    float* dst = t_ln + (size_t)(row - 8192) * 512 + lane * 8;
    *(float4*)dst       = make_float4(y[0], y[1], y[2], y[3]);
    *(float4*)(dst + 4) = make_float4(y[4], y[5], y[6], y[7]);
  }
}

// ---- kernel 3: tab token k/v (block per batch, coalesced) -----------------
__global__ __launch_bounds__(256) void k_tab(const float* __restrict__ t_ln,
                                             const float* __restrict__ w_tab,
                                             unsigned short* __restrict__ kh,
                                             unsigned short* __restrict__ vt) {
  __shared__ float tl[512];
  int b = blockIdx.x, t = threadIdx.x;
  tl[t] = t_ln[b * 512 + t];
  tl[t + 256] = t_ln[b * 512 + t + 256];
  __syncthreads();
  float s[4] = {0.f, 0.f, 0.f, 0.f};
  for (int k = 0; k < 512; ++k) {
    float a = tl[k];
    #pragma unroll
    for (int i = 0; i < 4; ++i)
      s[i] += a * w_tab[(size_t)k * 1536 + 512 + i * 256 + t];
  }
  #pragma unroll
  for (int i = 0; i < 4; ++i) {
    int g = i * 256 + t;          // 0..1023 over [k | v] x [h] x [d]
    int part = g >> 9, hd = g & 511, h = hd >> 6, d = hd & 63;
    int bh = b * 8 + h;
    unsigned short hv = f2bf(s[i]);
    if (part == 0) kh[((size_t)bh * 1056 + 1024) * 64 + d] = hv;
    else           vt[((size_t)bh * 64 + d) * 1056 + 1024] = hv;
  }
}

// ---- kernel 4: QKV GEMM, m97 structure ------------------------------------
// C[8192][1536] = x_bf @ wqt^T. 128x128 block tile, 4 waves of 64x64, BK=32.
// global_load_lds (w=16) staging, 2-barrier K-loop. Scatter epilogue.
__global__ __launch_bounds__(256) void k_qkv(const unsigned short* __restrict__ x_bf,
                                             const unsigned short* __restrict__ wqt,
                                             unsigned short* __restrict__ qh,
                                             unsigned short* __restrict__ kh,
                                             unsigned short* __restrict__ vt) {
  __shared__ unsigned short As[128 * 32];
  __shared__ unsigned short Bs[128 * 32];
  int tid = threadIdx.x;
  int wid = tid >> 6, lane = tid & 63;
  int bm = blockIdx.x & 63, bn = blockIdx.x >> 6;   // 64 x 12
  int r0 = bm * 128, c0 = bn * 128;
  int lr = lane & 15, lk = (lane >> 4) * 8;
  int wr = (wid >> 1) * 64, wc = (wid & 1) * 64;
  int srow = lane >> 2, scol = (lane & 3) * 8;      // staging lane mapping
  const unsigned short* gA0 = x_bf + (size_t)(r0 + (wid * 2 + 0) * 16 + srow) * 512 + scol;
  const unsigned short* gA1 = x_bf + (size_t)(r0 + (wid * 2 + 1) * 16 + srow) * 512 + scol;
  const unsigned short* gB0 = wqt  + (size_t)(c0 + (wid * 2 + 0) * 16 + srow) * 512 + scol;
  const unsigned short* gB1 = wqt  + (size_t)(c0 + (wid * 2 + 1) * 16 + srow) * 512 + scol;
  unsigned short* lA0 = &As[(wid * 2 + 0) * 512];
  unsigned short* lA1 = &As[(wid * 2 + 1) * 512];
  unsigned short* lB0 = &Bs[(wid * 2 + 0) * 512];
  unsigned short* lB1 = &Bs[(wid * 2 + 1) * 512];

  f32x4 acc[4][4];
  #pragma unroll
  for (int mi = 0; mi < 4; ++mi)
    #pragma unroll
    for (int ni = 0; ni < 4; ++ni)
      acc[mi][ni] = (f32x4){0.f, 0.f, 0.f, 0.f};

  for (int k0 = 0; k0 < 512; k0 += 32) {
    GLD16(gA0 + k0, lA0);
    GLD16(gA1 + k0, lA1);
    GLD16(gB0 + k0, lB0);
    GLD16(gB1 + k0, lB1);
    __syncthreads();
    bf16x8 af[4], bfr[4];
    #pragma unroll
    for (int mi = 0; mi < 4; ++mi)
      af[mi] = *(const bf16x8*)&As[(wr + mi * 16 + lr) * 32 + lk];
    #pragma unroll
    for (int ni = 0; ni < 4; ++ni)
      bfr[ni] = *(const bf16x8*)&Bs[(wc + ni * 16 + lr) * 32 + lk];
    #pragma unroll
    for (int mi = 0; mi < 4; ++mi)
      #pragma unroll
      for (int ni = 0; ni < 4; ++ni)
        acc[mi][ni] = MFMA16(af[mi], bfr[ni], acc[mi][ni]);
    __syncthreads();
  }

  #pragma unroll
  for (int ni = 0; ni < 4; ++ni) {
    int col0 = c0 + wc + ni * 16;
    int which = col0 >> 9;
    int hh = (col0 & 511) >> 6;
    int d = (col0 & 63) + lr;
    #pragma unroll
    for (int mi = 0; mi < 4; ++mi)
      #pragma unroll
      for (int reg = 0; reg < 4; ++reg) {
        int row = r0 + wr + mi * 16 + (lane >> 4) * 4 + reg;
        int b = row >> 10, n = row & 1023;
        int bh = b * 8 + hh;
        float v = acc[mi][ni][reg];
        if (which == 0) {
          qh[((size_t)bh * 1024 + n) * 64 + d] = f2bf(v * QSCALE);
        } else if (which == 1) {
          kh[((size_t)bh * 1056 + n) * 64 + d] = f2bf(v);
        } else {
          vt[((size_t)bh * 64 + d) * 1056 + n] = f2bf(v);
        }
      }
  }
}

// ---- kernel 5: flash attention, swapped-operand 32x32 MFMA ----------------
__global__ __launch_bounds__(256) void k_attn(const unsigned short* __restrict__ qh,
                                              const unsigned short* __restrict__ kh,
                                              const unsigned short* __restrict__ vt,
                                              unsigned short* __restrict__ ao) {
  int wid = threadIdx.x >> 6, lane = threadIdx.x & 63;
  int wave = blockIdx.x * 4 + wid;
  int bh = wave >> 5, qt = wave & 31;
  int q0 = qt * 32;
  int lq = lane & 31;          // q / key / d row within 32-group
  int half = lane >> 5;        // k-subchunk selector
  const unsigned short* Q = qh + (size_t)bh * 1024 * 64;
  const unsigned short* K = kh + (size_t)bh * 1056 * 64;
  const unsigned short* V = vt + (size_t)bh * 64 * 1056;

  const unsigned short* qlane = Q + (size_t)(q0 + lq) * 64 + half * 8;
  const unsigned short* klane = K + (size_t)lq * 64 + half * 8;
  const unsigned short* vlane = V + (size_t)lq * 1056 + half * 8;

  bf16x8 qf[4];
  #pragma unroll
  for (int dt = 0; dt < 4; ++dt)
    qf[dt] = *(const bf16x8*)(qlane + dt * 16);

  bf16x8 kf[4], kfn[4];
  #pragma unroll
  for (int dt = 0; dt < 4; ++dt)
    kf[dt] = *(const bf16x8*)(klane + dt * 16);

  f32x16 o0 = (f32x16)(0.0f), o1 = (f32x16)(0.0f);
  float m = -1e30f, lsum = 0.f;

  for (int kt = 0; kt < 33; ++kt) {
    bf16x8 vf00 = *(const bf16x8*)(vlane + kt * 32);
    bf16x8 vf01 = *(const bf16x8*)(vlane + kt * 32 + 16);
    bf16x8 vf10 = *(const bf16x8*)(vlane + 32 * 1056 + kt * 32);
    bf16x8 vf11 = *(const bf16x8*)(vlane + 32 * 1056 + kt * 32 + 16);
    if (kt < 32) {
      #pragma unroll
      for (int dt = 0; dt < 4; ++dt)
        kfn[dt] = *(const bf16x8*)(klane + (kt + 1) * 2048 + dt * 16);
    }
    f32x16 s = (f32x16)(0.0f);
    #pragma unroll
    for (int dt = 0; dt < 4; ++dt)
      s = MFMA32(kf[dt], qf[dt], s);
    if (kt == 32) {
      #pragma unroll
      for (int reg = 0; reg < 16; ++reg) {
        if (reg == 0) { if (half) s[0] = -1e30f; }
        else s[reg] = -1e30f;
      }
    }
    float pmax = s[0];
    #pragma unroll
    for (int reg = 1; reg < 16; ++reg) pmax = fmaxf(pmax, s[reg]);
    pmax = fmaxf(pmax, __shfl_xor(pmax, 32));
    if (!__all(pmax <= m + 8.0f)) {
      float mnew = fmaxf(m, pmax);
      float al = __builtin_amdgcn_exp2f(m - mnew);
      lsum *= al;
      #pragma unroll
      for (int reg = 0; reg < 16; ++reg) { o0[reg] *= al; o1[reg] *= al; }
      m = mnew;
    }
    float p[16];
    float ls = 0.f;
    #pragma unroll
    for (int reg = 0; reg < 16; ++reg) {
      p[reg] = __builtin_amdgcn_exp2f(s[reg] - m);
      ls += p[reg];
    }
    lsum += ls;
    unsigned int c0x0 = cvtpk_bf16(p[0],  p[1]);
    unsigned int c0x1 = cvtpk_bf16(p[2],  p[3]);
    unsigned int c0y0 = cvtpk_bf16(p[4],  p[5]);
    unsigned int c0y1 = cvtpk_bf16(p[6],  p[7]);
    unsigned int c1x0 = cvtpk_bf16(p[8],  p[9]);
    unsigned int c1x1 = cvtpk_bf16(p[10], p[11]);
    unsigned int c1y0 = cvtpk_bf16(p[12], p[13]);
    unsigned int c1y1 = cvtpk_bf16(p[14], p[15]);
    asm volatile("v_permlane32_swap_b32 %0, %1" : "+v"(c0x0), "+v"(c0y0));
    asm volatile("v_permlane32_swap_b32 %0, %1" : "+v"(c0x1), "+v"(c0y1));
    asm volatile("v_permlane32_swap_b32 %0, %1" : "+v"(c1x0), "+v"(c1y0));
    asm volatile("v_permlane32_swap_b32 %0, %1" : "+v"(c1x1), "+v"(c1y1));
    union { unsigned int w[4]; bf16x8 v; } f0, f1;
    f0.w[0] = c0x0; f0.w[1] = c0x1; f0.w[2] = c0y0; f0.w[3] = c0y1;
    f1.w[0] = c1x0; f1.w[1] = c1x1; f1.w[2] = c1y0; f1.w[3] = c1y1;
    o0 = MFMA32(vf00, f0.v, o0);
    o0 = MFMA32(vf01, f1.v, o0);
    o1 = MFMA32(vf10, f0.v, o1);
    o1 = MFMA32(vf11, f1.v, o1);
    #pragma unroll
    for (int dt = 0; dt < 4; ++dt) kf[dt] = kfn[dt];
  }
  lsum += __shfl_xor(lsum, 32);
  float rl = 1.0f / lsum;
  int b = bh >> 3, h = bh & 7;
  unsigned short* aorow = ao + ((size_t)(b * 1024 + q0 + lq)) * 512 + h * 64;
  #pragma unroll
  for (int dt2 = 0; dt2 < 2; ++dt2) {
    #pragma unroll
    for (int g = 0; g < 4; ++g) {
      ushort4 pk;
      float v0 = (dt2 ? o1[4 * g + 0] : o0[4 * g + 0]) * rl;
      float v1 = (dt2 ? o1[4 * g + 1] : o0[4 * g + 1]) * rl;
      float v2 = (dt2 ? o1[4 * g + 2] : o0[4 * g + 2]) * rl;
      float v3 = (dt2 ? o1[4 * g + 3] : o0[4 * g + 3]) * rl;
      pk.x = f2bf(v0); pk.y = f2bf(v1); pk.z = f2bf(v2); pk.w = f2bf(v3);
      *(ushort4*)(aorow + dt2 * 32 + 8 * g + 4 * half) = pk;
    }
  }
}

// ---- kernel 6: output GEMM + bias, m97 structure --------------------------
__global__ __launch_bounds__(256) void k_out(const unsigned short* __restrict__ ao,
                                             const unsigned short* __restrict__ wot,
                                             const float* __restrict__ b_out,
                                             float* __restrict__ out) {
  __shared__ unsigned short As[128 * 32];
  __shared__ unsigned short Bs[128 * 32];
  int tid = threadIdx.x;
  int wid = tid >> 6, lane = tid & 63;
  int bm = blockIdx.x & 63, bn = blockIdx.x >> 6;   // 64 x 4
  int r0 = bm * 128, c0 = bn * 128;
  int lr = lane & 15, lk = (lane >> 4) * 8;
  int wr = (wid >> 1) * 64, wc = (wid & 1) * 64;
  int srow = lane >> 2, scol = (lane & 3) * 8;
  const unsigned short* gA0 = ao  + (size_t)(r0 + (wid * 2 + 0) * 16 + srow) * 512 + scol;
  const unsigned short* gA1 = ao  + (size_t)(r0 + (wid * 2 + 1) * 16 + srow) * 512 + scol;
  const unsigned short* gB0 = wot + (size_t)(c0 + (wid * 2 + 0) * 16 + srow) * 512 + scol;
  const unsigned short* gB1 = wot + (size_t)(c0 + (wid * 2 + 1) * 16 + srow) * 512 + scol;
  unsigned short* lA0 = &As[(wid * 2 + 0) * 512];
  unsigned short* lA1 = &As[(wid * 2 + 1) * 512];
  unsigned short* lB0 = &Bs[(wid * 2 + 0) * 512];
  unsigned short* lB1 = &Bs[(wid * 2 + 1) * 512];

  f32x4 acc[4][4];
  #pragma unroll
  for (int mi = 0; mi < 4; ++mi)
    #pragma unroll
    for (int ni = 0; ni < 4; ++ni)
      acc[mi][ni] = (f32x4){0.f, 0.f, 0.f, 0.f};

  for (int k0 = 0; k0 < 512; k0 += 32) {
    GLD16(gA0 + k0, lA0);
    GLD16(gA1 + k0, lA1);
    GLD16(gB0 + k0, lB0);
    GLD16(gB1 + k0, lB1);
    __syncthreads();
    bf16x8 af[4], bfr[4];
    #pragma unroll
    for (int mi = 0; mi < 4; ++mi)
      af[mi] = *(const bf16x8*)&As[(wr + mi * 16 + lr) * 32 + lk];
    #pragma unroll
    for (int ni = 0; ni < 4; ++ni)
      bfr[ni] = *(const bf16x8*)&Bs[(wc + ni * 16 + lr) * 32 + lk];
    #pragma unroll
    for (int mi = 0; mi < 4; ++mi)
      #pragma unroll
      for (int ni = 0; ni < 4; ++ni)
        acc[mi][ni] = MFMA16(af[mi], bfr[ni], acc[mi][ni]);
    __syncthreads();
  }

  #pragma unroll
  for (int ni = 0; ni < 4; ++ni) {
    int col = c0 + wc + ni * 16 + lr;
    float bias = b_out[col];
    #pragma unroll
    for (int mi = 0; mi < 4; ++mi)
      #pragma unroll
      for (int reg = 0; reg < 4; ++reg) {
        int row = r0 + wr + mi * 16 + (lane >> 4) * 4 + reg;
        out[(size_t)row * 512 + col] = acc[mi][ni][reg] + bias;
      }
  }
}

// ---------------------------------------------------------------------------
extern "C" void kernel_launch(void* const* d_in, const int* in_sizes, int n_in,
                              void* d_out, int out_size, void* d_ws, size_t ws_size,
                              hipStream_t stream) {
  const float* img       = (const float*)d_in[0];
  const float* tab       = (const float*)d_in[1];
  const float* w_qkv     = (const float*)d_in[2];
  const float* w_tab_qkv = (const float*)d_in[3];
  const float* w_out     = (const float*)d_in[4];
  const float* b_out     = (const float*)d_in[5];
  const float* ln_w      = (const float*)d_in[6];
  const float* ln_b      = (const float*)d_in[7];
  char* ws = (char*)d_ws;
  unsigned short* x_bf = (unsigned short*)(ws);             //  8 MiB
  unsigned short* wqt  = (unsigned short*)(ws + 8388608);   //  1.5 MiB
  unsigned short* wot  = (unsigned short*)(ws + 9961472);   //  0.5 MiB
  unsigned short* qh   = (unsigned short*)(ws + 10485760);  //  8 MiB
  unsigned short* kh   = (unsigned short*)(ws + 18874368);  //  8.25 MiB
  unsigned short* vt   = (unsigned short*)(ws + 27525120);  //  8.25 MiB
  unsigned short* ao   = (unsigned short*)(ws + 36175872);  //  8 MiB
  float*          t_ln = (float*)(ws + 44564480);           //  16 KiB
  float* out = (float*)d_out;

  hipLaunchKernelGGL(k_prep, dim3(256),  dim3(256), 0, stream, w_qkv, w_out, wqt, wot);
  hipLaunchKernelGGL(k_ln,   dim3(2050), dim3(256), 0, stream, img, tab, ln_w, ln_b, x_bf, t_ln);
  hipLaunchKernelGGL(k_tab,  dim3(8),    dim3(256), 0, stream, t_ln, w_tab_qkv, kh, vt);
  hipLaunchKernelGGL(k_qkv,  dim3(768),  dim3(256), 0, stream, x_bf, wqt, qh, kh, vt);
  hipLaunchKernelGGL(k_attn, dim3(512),  dim3(256), 0, stream, qh, kh, vt, ao);
  hipLaunchKernelGGL(k_out,  dim3(256),  dim3(256), 0, stream, ao, wot, b_out, out);
}

// Round 4
// 146.091 us; speedup vs baseline: 1.4665x; 1.0073x over previous
//
#include <hip/hip_runtime.h>

// ---------------------------------------------------------------------------
// Attention_43868795961547: LN -> QKV -> MHA(1025 keys) -> proj
// b=8, n=1024, dim=512, heads=8, dh=64. bf16 MFMA, f32 accum.
// Round 4: k_attn + XCD-swizzle (blocks of same bh -> same XCD L2),
// V register double-buffer, s_setprio around MFMA clusters.
// ---------------------------------------------------------------------------

typedef __attribute__((ext_vector_type(4))) float f32x4;
typedef __attribute__((ext_vector_type(16))) float f32x16;
typedef __attribute__((ext_vector_type(8))) short bf16x8;

#define MFMA16(a, b, c) __builtin_amdgcn_mfma_f32_16x16x32_bf16(a, b, c, 0, 0, 0)
#define MFMA32(a, b, c) __builtin_amdgcn_mfma_f32_32x32x16_bf16(a, b, c, 0, 0, 0)

#define GLD16(gsrc, ldst)                                                     \
  __builtin_amdgcn_global_load_lds(                                           \
      (const __attribute__((address_space(1))) void*)(gsrc),                  \
      (__attribute__((address_space(3))) void*)(ldst), 16, 0, 0)

// Q pre-scale: dots*0.125 in exp2-domain => fold 0.125*log2(e) into Q.
#define QSCALE 0.18033688011112042f

__device__ __forceinline__ unsigned short f2bf(float f) {
  union { float f; unsigned int u; } c; c.f = f;
  unsigned int u = c.u;
  u += 0x7fffu + ((u >> 16) & 1u);   // RNE
  return (unsigned short)(u >> 16);
}

__device__ __forceinline__ unsigned int cvtpk_bf16(float lo, float hi) {
  unsigned int r;
  asm("v_cvt_pk_bf16_f32 %0, %1, %2" : "=v"(r) : "v"(lo), "v"(hi));
  return r;
}

// ---- kernel 1: tiled transpose+convert weights to bf16 --------------------
__global__ __launch_bounds__(256) void k_prep(const float* __restrict__ w_qkv,
                                              const float* __restrict__ w_out,
                                              unsigned short* __restrict__ wqt,
                                              unsigned short* __restrict__ wot) {
  __shared__ unsigned short t[64][68];
  int blk = blockIdx.x, tid = threadIdx.x;
  const float* src;
  unsigned short* dst;
  int k0, n0, ldin;
  if (blk < 192) {
    int ti = blk / 24, tj = blk % 24;
    k0 = ti * 64; n0 = tj * 64; ldin = 1536;
    src = w_qkv; dst = wqt;
  } else {
    int g = blk - 192;
    int ti = g >> 3, tj = g & 7;
    k0 = ti * 64; n0 = tj * 64; ldin = 512;
    src = w_out; dst = wot;
  }
  int rr = tid >> 4, c4 = (tid & 15) * 4;
  #pragma unroll
  for (int i = 0; i < 4; ++i) {
    int r = i * 16 + rr;
    float4 v = *(const float4*)(src + (size_t)(k0 + r) * ldin + n0 + c4);
    t[c4 + 0][r] = f2bf(v.x);
    t[c4 + 1][r] = f2bf(v.y);
    t[c4 + 2][r] = f2bf(v.z);
    t[c4 + 3][r] = f2bf(v.w);
  }
  __syncthreads();
  #pragma unroll
  for (int i = 0; i < 4; ++i) {
    int r = i * 16 + rr;
    ushort4 w = *(const ushort4*)&t[r][c4];
    *(ushort4*)(dst + (size_t)(n0 + r) * 512 + k0 + c4) = w;
  }
}

// ---- kernel 2: LayerNorm (wave per row) -----------------------------------
__global__ __launch_bounds__(256) void k_ln(const float* __restrict__ img,
                                            const float* __restrict__ tab,
                                            const float* __restrict__ ln_w,
                                            const float* __restrict__ ln_b,
                                            unsigned short* __restrict__ x_bf,
                                            float* __restrict__ t_ln) {
  int wid = threadIdx.x >> 6, lane = threadIdx.x & 63;
  int row = blockIdx.x * 4 + wid;
  if (row >= 8200) return;
  const float* src = (row < 8192) ? img + (size_t)row * 512
                                  : tab + (size_t)(row - 8192) * 512;
  float4 v0 = *(const float4*)(src + lane * 8);
  float4 v1 = *(const float4*)(src + lane * 8 + 4);
  float x[8] = {v0.x, v0.y, v0.z, v0.w, v1.x, v1.y, v1.z, v1.w};
  float s = 0.f, sq = 0.f;
  #pragma unroll
  for (int j = 0; j < 8; ++j) { s += x[j]; sq += x[j] * x[j]; }
  #pragma unroll
  for (int off = 32; off >= 1; off >>= 1) {
    s  += __shfl_xor(s, off);
    sq += __shfl_xor(sq, off);
  }
  float mean = s * (1.0f / 512.0f);
  float var  = sq * (1.0f / 512.0f) - mean * mean;
  float rs = rsqrtf(var + 1e-5f);
  float4 w0 = *(const float4*)(ln_w + lane * 8);
  float4 w1 = *(const float4*)(ln_w + lane * 8 + 4);
  float4 b0 = *(const float4*)(ln_b + lane * 8);
  float4 b1 = *(const float4*)(ln_b + lane * 8 + 4);
  float w[8] = {w0.x, w0.y, w0.z, w0.w, w1.x, w1.y, w1.z, w1.w};
  float bb[8] = {b0.x, b0.y, b0.z, b0.w, b1.x, b1.y, b1.z, b1.w};
  float y[8];
  #pragma unroll
  for (int j = 0; j < 8; ++j) y[j] = (x[j] - mean) * rs * w[j] + bb[j];
  if (row < 8192) {
    bf16x8 o;
    #pragma unroll
    for (int j = 0; j < 8; ++j) o[j] = (short)f2bf(y[j]);
    *(bf16x8*)(x_bf + (size_t)row * 512 + lane * 8) = o;
  } else {
    float* dst = t_ln + (size_t)(row - 8192) * 512 + lane * 8;
    *(float4*)dst       = make_float4(y[0], y[1], y[2], y[3]);
    *(float4*)(dst + 4) = make_float4(y[4], y[5], y[6], y[7]);
  }
}

// ---- kernel 3: tab token k/v (block per batch, coalesced) -----------------
__global__ __launch_bounds__(256) void k_tab(const float* __restrict__ t_ln,
                                             const float* __restrict__ w_tab,
                                             unsigned short* __restrict__ kh,
                                             unsigned short* __restrict__ vt) {
  __shared__ float tl[512];
  int b = blockIdx.x, t = threadIdx.x;
  tl[t] = t_ln[b * 512 + t];
  tl[t + 256] = t_ln[b * 512 + t + 256];
  __syncthreads();
  float s[4] = {0.f, 0.f, 0.f, 0.f};
  for (int k = 0; k < 512; ++k) {
    float a = tl[k];
    #pragma unroll
    for (int i = 0; i < 4; ++i)
      s[i] += a * w_tab[(size_t)k * 1536 + 512 + i * 256 + t];
  }
  #pragma unroll
  for (int i = 0; i < 4; ++i) {
    int g = i * 256 + t;
    int part = g >> 9, hd = g & 511, h = hd >> 6, d = hd & 63;
    int bh = b * 8 + h;
    unsigned short hv = f2bf(s[i]);
    if (part == 0) kh[((size_t)bh * 1056 + 1024) * 64 + d] = hv;
    else           vt[((size_t)bh * 64 + d) * 1056 + 1024] = hv;
  }
}

// ---- kernel 4: QKV GEMM, m97 structure ------------------------------------
__global__ __launch_bounds__(256) void k_qkv(const unsigned short* __restrict__ x_bf,
                                             const unsigned short* __restrict__ wqt,
                                             unsigned short* __restrict__ qh,
                                             unsigned short* __restrict__ kh,
                                             unsigned short* __restrict__ vt) {
  __shared__ unsigned short As[128 * 32];
  __shared__ unsigned short Bs[128 * 32];
  int tid = threadIdx.x;
  int wid = tid >> 6, lane = tid & 63;
  int bm = blockIdx.x & 63, bn = blockIdx.x >> 6;   // 64 x 12
  int r0 = bm * 128, c0 = bn * 128;
  int lr = lane & 15, lk = (lane >> 4) * 8;
  int wr = (wid >> 1) * 64, wc = (wid & 1) * 64;
  int srow = lane >> 2, scol = (lane & 3) * 8;
  const unsigned short* gA0 = x_bf + (size_t)(r0 + (wid * 2 + 0) * 16 + srow) * 512 + scol;
  const unsigned short* gA1 = x_bf + (size_t)(r0 + (wid * 2 + 1) * 16 + srow) * 512 + scol;
  const unsigned short* gB0 = wqt  + (size_t)(c0 + (wid * 2 + 0) * 16 + srow) * 512 + scol;
  const unsigned short* gB1 = wqt  + (size_t)(c0 + (wid * 2 + 1) * 16 + srow) * 512 + scol;
  unsigned short* lA0 = &As[(wid * 2 + 0) * 512];
  unsigned short* lA1 = &As[(wid * 2 + 1) * 512];
  unsigned short* lB0 = &Bs[(wid * 2 + 0) * 512];
  unsigned short* lB1 = &Bs[(wid * 2 + 1) * 512];

  f32x4 acc[4][4];
  #pragma unroll
  for (int mi = 0; mi < 4; ++mi)
    #pragma unroll
    for (int ni = 0; ni < 4; ++ni)
      acc[mi][ni] = (f32x4){0.f, 0.f, 0.f, 0.f};

  for (int k0 = 0; k0 < 512; k0 += 32) {
    GLD16(gA0 + k0, lA0);
    GLD16(gA1 + k0, lA1);
    GLD16(gB0 + k0, lB0);
    GLD16(gB1 + k0, lB1);
    __syncthreads();
    bf16x8 af[4], bfr[4];
    #pragma unroll
    for (int mi = 0; mi < 4; ++mi)
      af[mi] = *(const bf16x8*)&As[(wr + mi * 16 + lr) * 32 + lk];
    #pragma unroll
    for (int ni = 0; ni < 4; ++ni)
      bfr[ni] = *(const bf16x8*)&Bs[(wc + ni * 16 + lr) * 32 + lk];
    #pragma unroll
    for (int mi = 0; mi < 4; ++mi)
      #pragma unroll
      for (int ni = 0; ni < 4; ++ni)
        acc[mi][ni] = MFMA16(af[mi], bfr[ni], acc[mi][ni]);
    __syncthreads();
  }

  #pragma unroll
  for (int ni = 0; ni < 4; ++ni) {
    int col0 = c0 + wc + ni * 16;
    int which = col0 >> 9;
    int hh = (col0 & 511) >> 6;
    int d = (col0 & 63) + lr;
    #pragma unroll
    for (int mi = 0; mi < 4; ++mi)
      #pragma unroll
      for (int reg = 0; reg < 4; ++reg) {
        int row = r0 + wr + mi * 16 + (lane >> 4) * 4 + reg;
        int b = row >> 10, n = row & 1023;
        int bh = b * 8 + hh;
        float v = acc[mi][ni][reg];
        if (which == 0) {
          qh[((size_t)bh * 1024 + n) * 64 + d] = f2bf(v * QSCALE);
        } else if (which == 1) {
          kh[((size_t)bh * 1056 + n) * 64 + d] = f2bf(v);
        } else {
          vt[((size_t)bh * 64 + d) * 1056 + n] = f2bf(v);
        }
      }
  }
}

// ---- kernel 5: flash attention, swapped-operand 32x32 MFMA ----------------
// XCD swizzle: 512 blocks, 8 blocks per bh; remap so all blocks of one bh
// dispatch to the same XCD (p%8 fixed) -> K/V L2-resident per XCD.
__global__ __launch_bounds__(256) void k_attn(const unsigned short* __restrict__ qh,
                                              const unsigned short* __restrict__ kh,
                                              const unsigned short* __restrict__ vt,
                                              unsigned short* __restrict__ ao) {
  int wid = threadIdx.x >> 6, lane = threadIdx.x & 63;
  int bid = blockIdx.x;
  int swz = ((bid & 7) << 6) + (bid >> 3);      // bijective, 512 % 8 == 0
  int wave = swz * 4 + wid;
  int bh = wave >> 5, qt = wave & 31;
  int q0 = qt * 32;
  int lq = lane & 31;
  int half = lane >> 5;
  const unsigned short* Q = qh + (size_t)bh * 1024 * 64;
  const unsigned short* K = kh + (size_t)bh * 1056 * 64;
  const unsigned short* V = vt + (size_t)bh * 64 * 1056;

  const unsigned short* qlane = Q + (size_t)(q0 + lq) * 64 + half * 8;
  const unsigned short* klane = K + (size_t)lq * 64 + half * 8;
  const unsigned short* vlane = V + (size_t)lq * 1056 + half * 8;

  bf16x8 qf[4];
  #pragma unroll
  for (int dt = 0; dt < 4; ++dt)
    qf[dt] = *(const bf16x8*)(qlane + dt * 16);

  // K and V register double-buffers (tile 0 preload)
  bf16x8 kf[4], kfn[4], vf[4], vfn[4];
  #pragma unroll
  for (int dt = 0; dt < 4; ++dt)
    kf[dt] = *(const bf16x8*)(klane + dt * 16);
  vf[0] = *(const bf16x8*)(vlane);
  vf[1] = *(const bf16x8*)(vlane + 16);
  vf[2] = *(const bf16x8*)(vlane + 32 * 1056);
  vf[3] = *(const bf16x8*)(vlane + 32 * 1056 + 16);

  f32x16 o0 = (f32x16)(0.0f), o1 = (f32x16)(0.0f);
  float m = -1e30f, lsum = 0.f;

  for (int kt = 0; kt < 33; ++kt) {
    // prefetch next tile's K and V (full iteration of latency cover)
    if (kt < 32) {
      #pragma unroll
      for (int dt = 0; dt < 4; ++dt)
        kfn[dt] = *(const bf16x8*)(klane + (kt + 1) * 2048 + dt * 16);
      vfn[0] = *(const bf16x8*)(vlane + (kt + 1) * 32);
      vfn[1] = *(const bf16x8*)(vlane + (kt + 1) * 32 + 16);
      vfn[2] = *(const bf16x8*)(vlane + 32 * 1056 + (kt + 1) * 32);
      vfn[3] = *(const bf16x8*)(vlane + 32 * 1056 + (kt + 1) * 32 + 16);
    }
    // S^T[key][q] (exp2 domain; scale folded into Q)
    f32x16 s = (f32x16)(0.0f);
    __builtin_amdgcn_s_setprio(1);
    #pragma unroll
    for (int dt = 0; dt < 4; ++dt)
      s = MFMA32(kf[dt], qf[dt], s);
    __builtin_amdgcn_s_setprio(0);
    if (kt == 32) {
      #pragma unroll
      for (int reg = 0; reg < 16; ++reg) {
        if (reg == 0) { if (half) s[0] = -1e30f; }
        else s[reg] = -1e30f;
      }
    }
    float pmax = s[0];
    #pragma unroll
    for (int reg = 1; reg < 16; ++reg) pmax = fmaxf(pmax, s[reg]);
    pmax = fmaxf(pmax, __shfl_xor(pmax, 32));
    if (!__all(pmax <= m + 8.0f)) {
      float mnew = fmaxf(m, pmax);
      float al = __builtin_amdgcn_exp2f(m - mnew);
      lsum *= al;
      #pragma unroll
      for (int reg = 0; reg < 16; ++reg) { o0[reg] *= al; o1[reg] *= al; }
      m = mnew;
    }
    float p[16];
    float ls = 0.f;
    #pragma unroll
    for (int reg = 0; reg < 16; ++reg) {
      p[reg] = __builtin_amdgcn_exp2f(s[reg] - m);
      ls += p[reg];
    }
    lsum += ls;
    unsigned int c0x0 = cvtpk_bf16(p[0],  p[1]);
    unsigned int c0x1 = cvtpk_bf16(p[2],  p[3]);
    unsigned int c0y0 = cvtpk_bf16(p[4],  p[5]);
    unsigned int c0y1 = cvtpk_bf16(p[6],  p[7]);
    unsigned int c1x0 = cvtpk_bf16(p[8],  p[9]);
    unsigned int c1x1 = cvtpk_bf16(p[10], p[11]);
    unsigned int c1y0 = cvtpk_bf16(p[12], p[13]);
    unsigned int c1y1 = cvtpk_bf16(p[14], p[15]);
    asm volatile("v_permlane32_swap_b32 %0, %1" : "+v"(c0x0), "+v"(c0y0));
    asm volatile("v_permlane32_swap_b32 %0, %1" : "+v"(c0x1), "+v"(c0y1));
    asm volatile("v_permlane32_swap_b32 %0, %1" : "+v"(c1x0), "+v"(c1y0));
    asm volatile("v_permlane32_swap_b32 %0, %1" : "+v"(c1x1), "+v"(c1y1));
    union { unsigned int w[4]; bf16x8 v; } f0, f1;
    f0.w[0] = c0x0; f0.w[1] = c0x1; f0.w[2] = c0y0; f0.w[3] = c0y1;
    f1.w[0] = c1x0; f1.w[1] = c1x1; f1.w[2] = c1y0; f1.w[3] = c1y1;
    __builtin_amdgcn_s_setprio(1);
    o0 = MFMA32(vf[0], f0.v, o0);
    o0 = MFMA32(vf[1], f1.v, o0);
    o1 = MFMA32(vf[2], f0.v, o1);
    o1 = MFMA32(vf[3], f1.v, o1);
    __builtin_amdgcn_s_setprio(0);
    #pragma unroll
    for (int dt = 0; dt < 4; ++dt) { kf[dt] = kfn[dt]; vf[dt] = vfn[dt]; }
  }
  lsum += __shfl_xor(lsum, 32);
  float rl = 1.0f / lsum;
  int b = bh >> 3, h = bh & 7;
  unsigned short* aorow = ao + ((size_t)(b * 1024 + q0 + lq)) * 512 + h * 64;
  #pragma unroll
  for (int dt2 = 0; dt2 < 2; ++dt2) {
    #pragma unroll
    for (int g = 0; g < 4; ++g) {
      ushort4 pk;
      float v0 = (dt2 ? o1[4 * g + 0] : o0[4 * g + 0]) * rl;
      float v1 = (dt2 ? o1[4 * g + 1] : o0[4 * g + 1]) * rl;
      float v2 = (dt2 ? o1[4 * g + 2] : o0[4 * g + 2]) * rl;
      float v3 = (dt2 ? o1[4 * g + 3] : o0[4 * g + 3]) * rl;
      pk.x = f2bf(v0); pk.y = f2bf(v1); pk.z = f2bf(v2); pk.w = f2bf(v3);
      *(ushort4*)(aorow + dt2 * 32 + 8 * g + 4 * half) = pk;
    }
  }
}

// ---- kernel 6: output GEMM + bias, m97 structure --------------------------
__global__ __launch_bounds__(256) void k_out(const unsigned short* __restrict__ ao,
                                             const unsigned short* __restrict__ wot,
                                             const float* __restrict__ b_out,
                                             float* __restrict__ out) {
  __shared__ unsigned short As[128 * 32];
  __shared__ unsigned short Bs[128 * 32];
  int tid = threadIdx.x;
  int wid = tid >> 6, lane = tid & 63;
  int bm = blockIdx.x & 63, bn = blockIdx.x >> 6;   // 64 x 4
  int r0 = bm * 128, c0 = bn * 128;
  int lr = lane & 15, lk = (lane >> 4) * 8;
  int wr = (wid >> 1) * 64, wc = (wid & 1) * 64;
  int srow = lane >> 2, scol = (lane & 3) * 8;
  const unsigned short* gA0 = ao  + (size_t)(r0 + (wid * 2 + 0) * 16 + srow) * 512 + scol;
  const unsigned short* gA1 = ao  + (size_t)(r0 + (wid * 2 + 1) * 16 + srow) * 512 + scol;
  const unsigned short* gB0 = wot + (size_t)(c0 + (wid * 2 + 0) * 16 + srow) * 512 + scol;
  const unsigned short* gB1 = wot + (size_t)(c0 + (wid * 2 + 1) * 16 + srow) * 512 + scol;
  unsigned short* lA0 = &As[(wid * 2 + 0) * 512];
  unsigned short* lA1 = &As[(wid * 2 + 1) * 512];
  unsigned short* lB0 = &Bs[(wid * 2 + 0) * 512];
  unsigned short* lB1 = &Bs[(wid * 2 + 1) * 512];

  f32x4 acc[4][4];
  #pragma unroll
  for (int mi = 0; mi < 4; ++mi)
    #pragma unroll
    for (int ni = 0; ni < 4; ++ni)
      acc[mi][ni] = (f32x4){0.f, 0.f, 0.f, 0.f};

  for (int k0 = 0; k0 < 512; k0 += 32) {
    GLD16(gA0 + k0, lA0);
    GLD16(gA1 + k0, lA1);
    GLD16(gB0 + k0, lB0);
    GLD16(gB1 + k0, lB1);
    __syncthreads();
    bf16x8 af[4], bfr[4];
    #pragma unroll
    for (int mi = 0; mi < 4; ++mi)
      af[mi] = *(const bf16x8*)&As[(wr + mi * 16 + lr) * 32 + lk];
    #pragma unroll
    for (int ni = 0; ni < 4; ++ni)
      bfr[ni] = *(const bf16x8*)&Bs[(wc + ni * 16 + lr) * 32 + lk];
    #pragma unroll
    for (int mi = 0; mi < 4; ++mi)
      #pragma unroll
      for (int ni = 0; ni < 4; ++ni)
        acc[mi][ni] = MFMA16(af[mi], bfr[ni], acc[mi][ni]);
    __syncthreads();
  }

  #pragma unroll
  for (int ni = 0; ni < 4; ++ni) {
    int col = c0 + wc + ni * 16 + lr;
    float bias = b_out[col];
    #pragma unroll
    for (int mi = 0; mi < 4; ++mi)
      #pragma unroll
      for (int reg = 0; reg < 4; ++reg) {
        int row = r0 + wr + mi * 16 + (lane >> 4) * 4 + reg;
        out[(size_t)row * 512 + col] = acc[mi][ni][reg] + bias;
      }
  }
}

// ---------------------------------------------------------------------------
extern "C" void kernel_launch(void* const* d_in, const int* in_sizes, int n_in,
                              void* d_out, int out_size, void* d_ws, size_t ws_size,
                              hipStream_t stream) {
  const float* img       = (const float*)d_in[0];
  const float* tab       = (const float*)d_in[1];
  const float* w_qkv     = (const float*)d_in[2];
  const float* w_tab_qkv = (const float*)d_in[3];
  const float* w_out     = (const float*)d_in[4];
  const float* b_out     = (const float*)d_in[5];
  const float* ln_w      = (const float*)d_in[6];
  const float* ln_b      = (const float*)d_in[7];
  char* ws = (char*)d_ws;
  unsigned short* x_bf = (unsigned short*)(ws);             //  8 MiB
  unsigned short* wqt  = (unsigned short*)(ws + 8388608);   //  1.5 MiB
  unsigned short* wot  = (unsigned short*)(ws + 9961472);   //  0.5 MiB
  unsigned short* qh   = (unsigned short*)(ws + 10485760);  //  8 MiB
  unsigned short* kh   = (unsigned short*)(ws + 18874368);  //  8.25 MiB
  unsigned short* vt   = (unsigned short*)(ws + 27525120);  //  8.25 MiB
  unsigned short* ao   = (unsigned short*)(ws + 36175872);  //  8 MiB
  float*          t_ln = (float*)(ws + 44564480);           //  16 KiB
  float* out = (float*)d_out;

  hipLaunchKernelGGL(k_prep, dim3(256),  dim3(256), 0, stream, w_qkv, w_out, wqt, wot);
  hipLaunchKernelGGL(k_ln,   dim3(2050), dim3(256), 0, stream, img, tab, ln_w, ln_b, x_bf, t_ln);
  hipLaunchKernelGGL(k_tab,  dim3(8),    dim3(256), 0, stream, t_ln, w_tab_qkv, kh, vt);
  hipLaunchKernelGGL(k_qkv,  dim3(768),  dim3(256), 0, stream, x_bf, wqt, qh, kh, vt);
  hipLaunchKernelGGL(k_attn, dim3(512),  dim3(256), 0, stream, qh, kh, vt, ao);
  hipLaunchKernelGGL(k_out,  dim3(256),  dim3(256), 0, stream, ao, wot, b_out, out);
}